// Round 9
// baseline (448.677 us; speedup 1.0000x reference)
//
#include <hip/hip_runtime.h>

// SelfSeqAtten: h (S=1024, B=32, D=512) fp32, h_mask (B, S) int32
// out0 = (S,B,D) fp32, out1 = alpha (B,S,S) fp32, concatenated in d_out.
// ws layout: hb16 (B,S,D) fp16 [32MB] | hbT16 (B,D,S) fp16 [32MB]  (needs 64MB ws)

#define S_LEN 1024
#define B_LEN 32
#define D_LEN 512

typedef short short8 __attribute__((ext_vector_type(8)));
typedef _Float16 half8 __attribute__((ext_vector_type(8)));
typedef float float4v __attribute__((ext_vector_type(4)));
typedef float float4a __attribute__((ext_vector_type(4)));
typedef unsigned short ushort4v __attribute__((ext_vector_type(4)));

__device__ __forceinline__ unsigned short f2h(float f) {
  _Float16 h = (_Float16)f;            // RNE fp32->fp16 (v_cvt_f16_f32)
  return __builtin_bit_cast(unsigned short, h);
}

__device__ __forceinline__ float4a mfma16(short8 a, short8 b, float4a c) {
  return __builtin_amdgcn_mfma_f32_16x16x32_f16(
      __builtin_bit_cast(half8, a), __builtin_bit_cast(half8, b), c, 0, 0, 0);
}

// ---------------------------------------------------------------------------
// K0: cast h(S,B,D) fp32 -> hb(b,s,d) fp16  and  hbT(b,d,s) fp16 (LDS transpose)
// grid: 32*16*8 = 4096 blocks of 256
// ---------------------------------------------------------------------------
__global__ __launch_bounds__(256) void k_prep(const float* __restrict__ h,
                                              unsigned short* __restrict__ hb,
                                              unsigned short* __restrict__ hbT) {
  __shared__ __align__(16) unsigned short tile[64][68];  // pad 68: conflict-light col reads
  int blk = blockIdx.x;
  int b  = blk >> 7;          // /128
  int st = (blk >> 3) & 15;
  int dt = blk & 7;
  int s0 = st << 6, d0 = dt << 6;
  int tid = threadIdx.x;
#pragma unroll
  for (int i = 0; i < 4; ++i) {
    int idx = (i << 8) + tid;
    int sl = idx >> 4;        // 0..63 (s within tile)
    int dq = idx & 15;        // *4 floats (d within tile)
    float4v v = *(const float4v*)(h + ((size_t)(s0 + sl) * B_LEN + b) * D_LEN + d0 + (dq << 2));
    ushort4v o;
    o.x = f2h(v.x); o.y = f2h(v.y); o.z = f2h(v.z); o.w = f2h(v.w);
    *(ushort4v*)(hb + ((size_t)b * S_LEN + (s0 + sl)) * D_LEN + d0 + (dq << 2)) = o;
    *(ushort4v*)(&tile[sl][dq << 2]) = o;
  }
  __syncthreads();
#pragma unroll
  for (int i = 0; i < 4; ++i) {
    int idx = (i << 8) + tid;
    int dl = idx >> 4;        // d within tile
    int sq = idx & 15;        // *4 s
    ushort4v o;
    o.x = tile[(sq << 2) + 0][dl];
    o.y = tile[(sq << 2) + 1][dl];
    o.z = tile[(sq << 2) + 2][dl];
    o.w = tile[(sq << 2) + 3][dl];
    *(ushort4v*)(hbT + ((size_t)b * D_LEN + (d0 + dl)) * S_LEN + s0 + (sq << 2)) = o;
  }
}

// ---------------------------------------------------------------------------
// K1: scores + masked softmax + write alpha.
// One block = (batch b, 32-row strip). 512 threads = 8 waves in 2(M)x4(N).
// ---------------------------------------------------------------------------
__global__ __launch_bounds__(512) void k_scores(const unsigned short* __restrict__ hb,
                                                const int* __restrict__ h_mask,
                                                float* __restrict__ alpha) {
  __shared__ __align__(16) unsigned short sA[32 * 512];   // A strip, XOR-swizzled
  __shared__ __align__(16) unsigned short sB[128 * 128];  // B tile,  XOR-swizzled
  __shared__ float smsk[S_LEN];
  __shared__ float sred[2][4][32];

  int wg = blockIdx.x;                       // 0..1023
  int swz = ((wg & 7) << 7) + (wg >> 3);     // XCD-contiguous (1024 % 8 == 0)
  int b  = swz >> 5;
  int rt = swz & 31;
  int r0 = rt << 5;

  int tid  = threadIdx.x;
  int wave = tid >> 6;
  int lane = tid & 63;
  int wm = wave >> 2;        // 0..1  (row half)
  int wn = wave & 3;         // 0..3  (col quarter within tt tile)
  int lhi = lane >> 4;       // 0..3
  int llo = lane & 15;

  const unsigned short* hbB = hb + (size_t)b * (S_LEN * D_LEN);
  char* sAb = (char*)sA;
  char* sBb = (char*)sB;

  for (int i = tid; i < S_LEN; i += 512) smsk[i] = (float)h_mask[b * S_LEN + i];

  // stage A: rows r0..r0+32, full K=512
#pragma unroll
  for (int i = 0; i < 4; ++i) {
    int c   = (i << 9) + tid;    // 0..2047
    int row = c >> 6;            // 64 chunks/row
    int kc  = c & 63;
    short8 v = *(const short8*)(hbB + (size_t)(r0 + row) * D_LEN + (kc << 3));
    *(short8*)(sAb + (((row << 10) + (kc << 4)) ^ ((row & 7) << 4))) = v;
  }
  __syncthreads();

  float4a acc[8][2];
#pragma unroll
  for (int tt = 0; tt < 8; ++tt)
#pragma unroll
    for (int nf = 0; nf < 2; ++nf)
      acc[tt][nf] = (float4a){0.f, 0.f, 0.f, 0.f};

  for (int tt = 0; tt < 8; ++tt) {
    for (int kk = 0; kk < 4; ++kk) {
      if (tt | kk) __syncthreads();
      // stage B tile: hb rows tt*128..+128, k = kk*128..+128  ([128][128] fp16)
#pragma unroll
      for (int i = 0; i < 4; ++i) {
        int c   = (i << 9) + tid;
        int row = c >> 4;          // 16 chunks/row
        int kc  = c & 15;
        short8 v = *(const short8*)(hbB + (size_t)(tt * 128 + row) * D_LEN + kk * 128 + (kc << 3));
        *(short8*)(sBb + (((row << 8) + (kc << 4)) ^ ((row & 7) << 4))) = v;
      }
      __syncthreads();
#pragma unroll
      for (int ks = 0; ks < 4; ++ks) {
        int kb = (ks << 6) + (lhi << 4);             // byte offset of lane's 8 fp16
        int arow = (wm << 4) + llo;
        short8 af = *(const short8*)(sAb + (((arow << 10) + (kk << 8) + kb) ^ ((arow & 7) << 4)));
#pragma unroll
        for (int nf = 0; nf < 2; ++nf) {
          int trow = (wn << 5) + (nf << 4) + llo;
          short8 bfr = *(const short8*)(sBb + (((trow << 8) + kb) ^ ((trow & 7) << 4)));
          acc[tt][nf] = mfma16(af, bfr, acc[tt][nf]);
        }
      }
    }
  }

  // ---- masked softmax over the 32x1024 strip ----
  // D layout: col = llo (+16*nf+32*wn+128*tt), row = wm*16 + lhi*4 + r
  int rbase = (wm << 4) + (lhi << 2);
  float pmax[4] = {-1e30f, -1e30f, -1e30f, -1e30f};
#pragma unroll
  for (int tt = 0; tt < 8; ++tt) {
#pragma unroll
    for (int nf = 0; nf < 2; ++nf) {
      int col = (tt << 7) + (wn << 5) + (nf << 4) + llo;
      float m = smsk[col];
#pragma unroll
      for (int r = 0; r < 4; ++r) {
        float x = acc[tt][nf][r] * m;
        if (col == r0 + rbase + r) x = 0.f;   // diagonal zeroed (before mask-mult: same result)
        acc[tt][nf][r] = x;
        pmax[r] = fmaxf(pmax[r], x);
      }
    }
  }
#pragma unroll
  for (int d = 1; d < 16; d <<= 1)
#pragma unroll
    for (int r = 0; r < 4; ++r)
      pmax[r] = fmaxf(pmax[r], __shfl_xor(pmax[r], d));
  if (llo == 0) {
#pragma unroll
    for (int r = 0; r < 4; ++r) sred[0][wn][rbase + r] = pmax[r];
  }
  __syncthreads();
  float M[4];
#pragma unroll
  for (int r = 0; r < 4; ++r)
    M[r] = fmaxf(fmaxf(sred[0][0][rbase + r], sred[0][1][rbase + r]),
                 fmaxf(sred[0][2][rbase + r], sred[0][3][rbase + r]));

  float psum[4] = {0.f, 0.f, 0.f, 0.f};
#pragma unroll
  for (int tt = 0; tt < 8; ++tt) {
#pragma unroll
    for (int nf = 0; nf < 2; ++nf) {
      int col = (tt << 7) + (wn << 5) + (nf << 4) + llo;
      float m = smsk[col];
#pragma unroll
      for (int r = 0; r < 4; ++r) {
        float e = __expf(acc[tt][nf][r] - M[r]) * m;   // e = exp(x - max) * m
        acc[tt][nf][r] = e;
        psum[r] += e;
      }
    }
  }
#pragma unroll
  for (int d = 1; d < 16; d <<= 1)
#pragma unroll
    for (int r = 0; r < 4; ++r)
      psum[r] += __shfl_xor(psum[r], d);
  if (llo == 0) {
#pragma unroll
    for (int r = 0; r < 4; ++r) sred[1][wn][rbase + r] = psum[r];
  }
  __syncthreads();
  float rinv[4];
#pragma unroll
  for (int r = 0; r < 4; ++r) {
    float denom = sred[1][0][rbase + r] + sred[1][1][rbase + r] +
                  sred[1][2][rbase + r] + sred[1][3][rbase + r] + 1e-6f;
    rinv[r] = 1.0f / denom;
  }
  float* aB = alpha + (size_t)b * (S_LEN * S_LEN);
#pragma unroll
  for (int tt = 0; tt < 8; ++tt) {
#pragma unroll
    for (int nf = 0; nf < 2; ++nf) {
      int col = (tt << 7) + (wn << 5) + (nf << 4) + llo;
#pragma unroll
      for (int r = 0; r < 4; ++r)
        aB[(size_t)(r0 + rbase + r) * S_LEN + col] = acc[tt][nf][r] * rinv[r];
    }
  }
}

// ---------------------------------------------------------------------------
// K2: out = alpha @ hb.  Per batch: M=1024(s) N=512(d) K=1024(t).
// Tile 128x128, 256 threads = 4 waves (2x2), each wave 64x64.
// A = alpha fp32 -> fp16 on the fly; B^T = hbT (d-major, k=t contiguous).
// ---------------------------------------------------------------------------
__global__ __launch_bounds__(256) void k_out(const float* __restrict__ alpha,
                                             const unsigned short* __restrict__ hbT,
                                             float* __restrict__ out) {
  __shared__ __align__(16) unsigned short sA[128 * 64];
  __shared__ __align__(16) unsigned short sB[128 * 64];
  int wg = blockIdx.x;
  int swz = ((wg & 7) << 7) + (wg >> 3);
  int b  = swz >> 5;
  int r5 = swz & 31;
  int mt = r5 >> 2;
  int nt = r5 & 3;
  int m0 = mt << 7, n0 = nt << 7;
  int tid  = threadIdx.x;
  int wave = tid >> 6;
  int lane = tid & 63;
  int wm = wave >> 1, wn = wave & 1;
  int lhi = lane >> 4, llo = lane & 15;
  const float* A = alpha + (size_t)b * (S_LEN * S_LEN);
  const unsigned short* Bt = hbT + (size_t)b * (D_LEN * S_LEN);
  char* sAb = (char*)sA;
  char* sBb = (char*)sB;

  float4a acc[4][4];
#pragma unroll
  for (int mf = 0; mf < 4; ++mf)
#pragma unroll
    for (int nf = 0; nf < 4; ++nf)
      acc[mf][nf] = (float4a){0.f, 0.f, 0.f, 0.f};

  for (int kk = 0; kk < 16; ++kk) {
    if (kk) __syncthreads();
    // stage A: 128 rows x 64 k (fp32 -> fp16)
#pragma unroll
    for (int i = 0; i < 4; ++i) {
      int c   = (i << 8) + tid;   // 0..1023
      int row = c >> 3;           // 8 chunks/row
      int kc  = c & 7;
      const float* src = A + (size_t)(m0 + row) * S_LEN + (kk << 6) + (kc << 3);
      float4v v0 = *(const float4v*)src;
      float4v v1 = *(const float4v*)(src + 4);
      short8 o;
      o[0] = (short)f2h(v0.x); o[1] = (short)f2h(v0.y);
      o[2] = (short)f2h(v0.z); o[3] = (short)f2h(v0.w);
      o[4] = (short)f2h(v1.x); o[5] = (short)f2h(v1.y);
      o[6] = (short)f2h(v1.z); o[7] = (short)f2h(v1.w);
      *(short8*)(sAb + (((row << 7) + (kc << 4)) ^ ((row & 7) << 4))) = o;
    }
    // stage Bt: 128 d-rows x 64 t (fp16 copy)
#pragma unroll
    for (int i = 0; i < 4; ++i) {
      int c   = (i << 8) + tid;
      int row = c >> 3;
      int kc  = c & 7;
      short8 v = *(const short8*)(Bt + (size_t)(n0 + row) * S_LEN + (kk << 6) + (kc << 3));
      *(short8*)(sBb + (((row << 7) + (kc << 4)) ^ ((row & 7) << 4))) = v;
    }
    __syncthreads();
#pragma unroll
    for (int ks = 0; ks < 2; ++ks) {
      int kb = (ks << 6) + (lhi << 4);
      short8 af[4], bfr[4];
#pragma unroll
      for (int mf = 0; mf < 4; ++mf) {
        int arow = (wm << 6) + (mf << 4) + llo;
        af[mf] = *(const short8*)(sAb + (((arow << 7) + kb) ^ ((arow & 7) << 4)));
      }
#pragma unroll
      for (int nf = 0; nf < 4; ++nf) {
        int brow = (wn << 6) + (nf << 4) + llo;
        bfr[nf] = *(const short8*)(sBb + (((brow << 7) + kb) ^ ((brow & 7) << 4)));
      }
#pragma unroll
      for (int mf = 0; mf < 4; ++mf)
#pragma unroll
        for (int nf = 0; nf < 4; ++nf)
          acc[mf][nf] = mfma16(af[mf], bfr[nf], acc[mf][nf]);
    }
  }
  // epilogue: out[s][b][d]
#pragma unroll
  for (int mf = 0; mf < 4; ++mf) {
#pragma unroll
    for (int rr = 0; rr < 4; ++rr) {
      int sg = m0 + (wm << 6) + (mf << 4) + (lhi << 2) + rr;
#pragma unroll
      for (int nf = 0; nf < 4; ++nf) {
        int dg = n0 + (wn << 6) + (nf << 4) + llo;
        out[((size_t)sg * B_LEN + b) * D_LEN + dg] = acc[mf][nf][rr];
      }
    }
  }
}

extern "C" void kernel_launch(void* const* d_in, const int* in_sizes, int n_in,
                              void* d_out, int out_size, void* d_ws, size_t ws_size,
                              hipStream_t stream) {
  const float* h      = (const float*)d_in[0];
  const int*   h_mask = (const int*)d_in[1];
  float* out   = (float*)d_out;
  float* alpha = out + (size_t)S_LEN * B_LEN * D_LEN;   // second output region
  unsigned short* hb  = (unsigned short*)d_ws;                       // 32 MB
  unsigned short* hbT = hb + (size_t)B_LEN * S_LEN * D_LEN;          // 32 MB

  k_prep  <<<4096, 256, 0, stream>>>(h, hb, hbT);
  k_scores<<<1024, 512, 0, stream>>>(hb, h_mask, alpha);
  k_out   <<<1024, 256, 0, stream>>>(alpha, hbT, out);
}